// Round 2
// baseline (125.085 us; speedup 1.0000x reference)
//
#include <hip/hip_runtime.h>
#include <cmath>

// Local contrast normalization, fused, float4/b128 LDS throughout.
// x: [64,512,512,1] f32. 9x9 Gaussian (separable), SAME zero padding.

struct W9 { float w[9]; };

#define HW 512
#define TS 32
// strides in float4 units
#define XS_S 13   // xs: 48 rows, 12 f4 valid (48 cols: ox-8..ox+39)
#define H1_S 11   // h1: 48 rows, 10 f4 valid (40 cols: ox-4..ox+35)
#define DD_S 11   // dd: 40 rows, 10 f4 valid (40 cols: ox-4..ox+35)
#define H2_S 9    // h2: 40 rows,  8 f4 valid (32 cols: ox..ox+31), aliases xs

__global__ __launch_bounds__(256, 6) void lcn_kernel(const float* __restrict__ x,
                                                     float* __restrict__ out,
                                                     W9 wts) {
    __shared__ float4 sm[48 * XS_S + 48 * H1_S + 40 * DD_S];
    float4* xs = sm;
    float4* h1 = sm + 48 * XS_S;
    float4* dd = sm + 48 * XS_S + 48 * H1_S;
    float4* h2 = sm;  // alias xs (xs dead after phase 2)

    const int tid = threadIdx.x;
    const int ox = blockIdx.x * TS, oy = blockIdx.y * TS;
    const float* xb = x + (size_t)blockIdx.z * HW * HW;

    float w[9];
#pragma unroll
    for (int i = 0; i < 9; ++i) w[i] = wts.w[i];

    // ---- p0: load x halo, 48 rows x 12 f4 (cols ox-8 .. ox+39), zero-padded ----
    for (int t = tid; t < 576; t += 256) {
        int r = t / 12, c4 = t % 12;
        int gy = oy - 8 + r;
        int gx = ox - 8 + c4 * 4;
        float4 v = {0.f, 0.f, 0.f, 0.f};
        if (gy >= 0 && gy < HW) {
            if (gx >= 0 && gx + 3 < HW) {
                v = *reinterpret_cast<const float4*>(xb + (size_t)gy * HW + gx);
            } else {
#pragma unroll
                for (int k = 0; k < 4; ++k) {
                    int g = gx + k;
                    if (g >= 0 && g < HW) (&v.x)[k] = xb[(size_t)gy * HW + g];
                }
            }
        }
        xs[r * XS_S + c4] = v;
    }
    __syncthreads();

    // ---- p1: h1 = h-conv(x). 48 rows x 10 f4. 3 reads -> 4 outputs ----
    for (int t = tid; t < 480; t += 256) {
        int r = t / 10, c4 = t % 10;
        float4 a = xs[r * XS_S + c4];
        float4 b = xs[r * XS_S + c4 + 1];
        float4 c = xs[r * XS_S + c4 + 2];
        float X[12] = {a.x, a.y, a.z, a.w, b.x, b.y, b.z, b.w, c.x, c.y, c.z, c.w};
        float4 o = {0.f, 0.f, 0.f, 0.f};
#pragma unroll
        for (int j = 0; j < 9; ++j) {
            o.x = fmaf(w[j], X[0 + j], o.x);
            o.y = fmaf(w[j], X[1 + j], o.y);
            o.z = fmaf(w[j], X[2 + j], o.z);
            o.w = fmaf(w[j], X[3 + j], o.w);
        }
        h1[r * H1_S + c4] = o;
    }
    __syncthreads();

    // ---- p2: mean = v-conv(h1); dd = x - mean (zeroed outside image) ----
    // 80 tasks: 10 f4-cols x 8 row-blocks of 5; 9-deep float4 ring
    if (tid < 80) {
        int rb = tid / 10, c4 = tid % 10;
        int r0 = rb * 5;
        float4 ring[9];
#pragma unroll
        for (int i = 0; i < 9; ++i) ring[i] = h1[(r0 + i) * H1_S + c4];
#pragma unroll
        for (int k = 0; k < 5; ++k) {
            if (k) ring[(k + 8) % 9] = h1[(r0 + 8 + k) * H1_S + c4];
            float4 m = {0.f, 0.f, 0.f, 0.f};
#pragma unroll
            for (int j = 0; j < 9; ++j) {
                const float4 h = ring[(k + j) % 9];
                m.x = fmaf(w[j], h.x, m.x);
                m.y = fmaf(w[j], h.y, m.y);
                m.z = fmaf(w[j], h.z, m.z);
                m.w = fmaf(w[j], h.w, m.w);
            }
            int r = r0 + k;
            float4 xv = xs[(r + 4) * XS_S + (c4 + 1)];
            int gy = oy - 4 + r;
            int gx0 = ox - 4 + c4 * 4;
            bool rin = (gy >= 0 && gy < HW);
            float4 d;
            d.x = (rin && gx0 + 0 >= 0 && gx0 + 0 < HW) ? xv.x - m.x : 0.f;
            d.y = (rin && gx0 + 1 >= 0 && gx0 + 1 < HW) ? xv.y - m.y : 0.f;
            d.z = (rin && gx0 + 2 >= 0 && gx0 + 2 < HW) ? xv.z - m.z : 0.f;
            d.w = (rin && gx0 + 3 >= 0 && gx0 + 3 < HW) ? xv.w - m.w : 0.f;
            dd[r * DD_S + c4] = d;
        }
    }
    __syncthreads();

    // ---- p3: h2 = h-conv(dd^2). 40 rows x 8 f4 ----
    for (int t = tid; t < 320; t += 256) {
        int r = t / 8, c4 = t % 8;
        float4 a = dd[r * DD_S + c4];
        float4 b = dd[r * DD_S + c4 + 1];
        float4 c = dd[r * DD_S + c4 + 2];
        float X[12] = {a.x * a.x, a.y * a.y, a.z * a.z, a.w * a.w,
                       b.x * b.x, b.y * b.y, b.z * b.z, b.w * b.w,
                       c.x * c.x, c.y * c.y, c.z * c.z, c.w * c.w};
        float4 o = {0.f, 0.f, 0.f, 0.f};
#pragma unroll
        for (int j = 0; j < 9; ++j) {
            o.x = fmaf(w[j], X[0 + j], o.x);
            o.y = fmaf(w[j], X[1 + j], o.y);
            o.z = fmaf(w[j], X[2 + j], o.z);
            o.w = fmaf(w[j], X[3 + j], o.w);
        }
        h2[r * H2_S + c4] = o;
    }
    __syncthreads();

    // ---- p4: n2 = v-conv(h2); out = keep ? dd/sqrt(n2) : dd ----
    // 32 tasks: 8 f4-cols x 4 row-blocks of 8
    if (tid < 32) {
        int rb = tid / 8, c4 = tid % 8;
        int r0 = rb * 8;
        float* ob = out + (size_t)blockIdx.z * HW * HW;
        float4 ring[9];
#pragma unroll
        for (int i = 0; i < 9; ++i) ring[i] = h2[(r0 + i) * H2_S + c4];
#pragma unroll
        for (int k = 0; k < 8; ++k) {
            if (k) ring[(k + 8) % 9] = h2[(r0 + 8 + k) * H2_S + c4];
            float4 n2 = {0.f, 0.f, 0.f, 0.f};
#pragma unroll
            for (int j = 0; j < 9; ++j) {
                const float4 h = ring[(k + j) % 9];
                n2.x = fmaf(w[j], h.x, n2.x);
                n2.y = fmaf(w[j], h.y, n2.y);
                n2.z = fmaf(w[j], h.z, n2.z);
                n2.w = fmaf(w[j], h.w, n2.w);
            }
            float4 dv = dd[(r0 + k + 4) * DD_S + (c4 + 1)];
            float4 o;
            {
                float nr = sqrtf(n2.x); o.x = (nr > 0.5f) ? dv.x / nr : dv.x;
            }
            {
                float nr = sqrtf(n2.y); o.y = (nr > 0.5f) ? dv.y / nr : dv.y;
            }
            {
                float nr = sqrtf(n2.z); o.z = (nr > 0.5f) ? dv.z / nr : dv.z;
            }
            {
                float nr = sqrtf(n2.w); o.w = (nr > 0.5f) ? dv.w / nr : dv.w;
            }
            *reinterpret_cast<float4*>(ob + (size_t)(oy + r0 + k) * HW + ox + c4 * 4) = o;
        }
    }
}

static W9 make_w() {
    // reference: sigmah = 9/6, exponent divides by 2*sigmah = 3.0
    double g[9], s = 0.0;
    for (int i = 0; i < 9; ++i) {
        double off = (double)i - 4.5;
        g[i] = exp(-(off * off) / 3.0);
        s += g[i];
    }
    W9 r;
    for (int i = 0; i < 9; ++i) r.w[i] = (float)(g[i] / s);
    return r;
}

extern "C" void kernel_launch(void* const* d_in, const int* in_sizes, int n_in,
                              void* d_out, int out_size, void* d_ws, size_t ws_size,
                              hipStream_t stream) {
    const float* x = (const float*)d_in[0];
    float* out = (float*)d_out;
    W9 w = make_w();
    dim3 grid(HW / TS, HW / TS, 64);  // 16 x 16 x 64
    lcn_kernel<<<grid, dim3(256), 0, stream>>>(x, out, w);
}

// Round 3
// 70.078 us; speedup vs baseline: 1.7849x; 1.7849x over previous
//
#include <hip/hip_runtime.h>
#include <cmath>

// Local contrast normalization, fused. x: [64,512,512,1] f32.
// 9x9 Gaussian (separable), SAME zero padding.
// Tile: 64 wide x 32 tall. LDS buffers contiguous (stride==width) so that
// every b128 access has 16 consecutive lanes -> 16 consecutive float4s
// in one row => conflict-free without padding/swizzle.

struct W9 { float w[9]; };

#define HW   512
#define HW4  128   // f4 per image row
#define TSY  32    // output tile height
#define NH1  18    // h1/dd width in f4 (72 cols: ox-4 .. ox+67)
#define NH2  16    // h2/out width in f4 (64 cols)
#define RH1  48    // h1 rows  (oy-8 .. oy+39)
#define RDD  40    // dd/h2 rows (oy-4 .. oy+35)

__device__ __forceinline__ float4 conv9(const float* X, const float* w) {
    float4 o = {0.f, 0.f, 0.f, 0.f};
#pragma unroll
    for (int j = 0; j < 9; ++j) {
        o.x = fmaf(w[j], X[j + 0], o.x);
        o.y = fmaf(w[j], X[j + 1], o.y);
        o.z = fmaf(w[j], X[j + 2], o.z);
        o.w = fmaf(w[j], X[j + 3], o.w);
    }
    return o;
}

__global__ __launch_bounds__(256, 6) void lcn_kernel(const float* __restrict__ x,
                                                     float* __restrict__ out,
                                                     W9 wts) {
    __shared__ float4 sm[RH1 * NH1 + RDD * NH1];  // 864 + 720 f4 = 25,344 B
    float4* h1 = sm;                 // [48][18]
    float4* dd = sm + RH1 * NH1;     // [40][18]
    float4* h2 = sm;                 // [40][16], aliases h1 (dead after p2)

    const int tid = threadIdx.x;
    const int oxf = blockIdx.x * (NH2);      // f4 col of output tile (64-wide => 16 f4)
    const int oy  = blockIdx.y * TSY;
    const float* xb = x + (size_t)blockIdx.z * HW * HW;
    float* ob = out + (size_t)blockIdx.z * HW * HW;

    float w[9];
#pragma unroll
    for (int i = 0; i < 9; ++i) w[i] = wts.w[i];

    // ---- p1: h1[r][m] = h-conv(x) at row oy-8+r, f4 col oxf-1+m ----
    // reads x f4 cols oxf-2+m .. oxf+m directly from global (L1/L2).
    for (int o = tid; o < RH1 * NH1; o += 256) {
        int r = o / NH1, m = o % NH1;
        int gy = oy - 8 + r;
        float4 o4 = {0.f, 0.f, 0.f, 0.f};
        if (gy >= 0 && gy < HW) {
            const float4* row = reinterpret_cast<const float4*>(xb + (size_t)gy * HW);
            float X[12];
#pragma unroll
            for (int k = 0; k < 3; ++k) {
                int g4 = oxf - 2 + m + k;
                float4 v = (g4 >= 0 && g4 < HW4) ? row[g4] : float4{0.f, 0.f, 0.f, 0.f};
                X[4 * k + 0] = v.x; X[4 * k + 1] = v.y;
                X[4 * k + 2] = v.z; X[4 * k + 3] = v.w;
            }
            o4 = conv9(X, w);
        }
        h1[o] = o4;
    }
    __syncthreads();

    // ---- p2: mean = v-conv(h1); dd = x - mean (zero outside image) ----
    // 144 threads: f4-col m (18) x 8 row-groups of 5; 9-deep register ring.
    if (tid < 144) {
        int m = tid % NH1, rg = tid / NH1;
        int r0 = rg * 5;
        int g4 = oxf - 1 + m;
        bool cin = (g4 >= 0 && g4 < HW4);
        float4 ring[9];
#pragma unroll
        for (int i = 0; i < 9; ++i) ring[i] = h1[(r0 + i) * NH1 + m];
#pragma unroll
        for (int k = 0; k < 5; ++k) {
            if (k) ring[(k + 8) % 9] = h1[(r0 + 8 + k) * NH1 + m];
            float4 mean = {0.f, 0.f, 0.f, 0.f};
#pragma unroll
            for (int j = 0; j < 9; ++j) {
                const float4 h = ring[(k + j) % 9];
                mean.x = fmaf(w[j], h.x, mean.x);
                mean.y = fmaf(w[j], h.y, mean.y);
                mean.z = fmaf(w[j], h.z, mean.z);
                mean.w = fmaf(w[j], h.w, mean.w);
            }
            int rp = r0 + k;
            int gy = oy - 4 + rp;
            float4 d = {0.f, 0.f, 0.f, 0.f};
            if (cin && gy >= 0 && gy < HW) {
                float4 xv = reinterpret_cast<const float4*>(xb + (size_t)gy * HW)[g4];
                d.x = xv.x - mean.x; d.y = xv.y - mean.y;
                d.z = xv.z - mean.z; d.w = xv.w - mean.w;
            }
            dd[rp * NH1 + m] = d;
        }
    }
    __syncthreads();

    // ---- p3: h2[r][n] = h-conv(dd^2), 40 rows x 16 f4 ----
    for (int o = tid; o < RDD * NH2; o += 256) {
        int r = o / NH2, n = o % NH2;
        float4 a = dd[r * NH1 + n];
        float4 b = dd[r * NH1 + n + 1];
        float4 c = dd[r * NH1 + n + 2];
        float X[12] = {a.x * a.x, a.y * a.y, a.z * a.z, a.w * a.w,
                       b.x * b.x, b.y * b.y, b.z * b.z, b.w * b.w,
                       c.x * c.x, c.y * c.y, c.z * c.z, c.w * c.w};
        h2[o] = conv9(X, w);   // o == r*16 + n, contiguous
    }
    __syncthreads();

    // ---- p4: n2 = v-conv(h2); out = keep ? dd/sqrt(n2) : dd ----
    // 128 threads: f4-col n (16) x 8 row-groups of 4; register ring.
    if (tid < 128) {
        int n = tid % NH2, rg = tid / NH2;
        int r0 = rg * 4;
        float4 ring[9];
#pragma unroll
        for (int i = 0; i < 9; ++i) ring[i] = h2[(r0 + i) * NH2 + n];
#pragma unroll
        for (int k = 0; k < 4; ++k) {
            if (k) ring[(k + 8) % 9] = h2[(r0 + 8 + k) * NH2 + n];
            float4 n2 = {0.f, 0.f, 0.f, 0.f};
#pragma unroll
            for (int j = 0; j < 9; ++j) {
                const float4 h = ring[(k + j) % 9];
                n2.x = fmaf(w[j], h.x, n2.x);
                n2.y = fmaf(w[j], h.y, n2.y);
                n2.z = fmaf(w[j], h.z, n2.z);
                n2.w = fmaf(w[j], h.w, n2.w);
            }
            float4 dv = dd[(r0 + k + 4) * NH1 + n + 1];
            float4 o;
            { float nr = sqrtf(n2.x); o.x = (nr > 0.5f) ? dv.x / nr : dv.x; }
            { float nr = sqrtf(n2.y); o.y = (nr > 0.5f) ? dv.y / nr : dv.y; }
            { float nr = sqrtf(n2.z); o.z = (nr > 0.5f) ? dv.z / nr : dv.z; }
            { float nr = sqrtf(n2.w); o.w = (nr > 0.5f) ? dv.w / nr : dv.w; }
            reinterpret_cast<float4*>(ob + (size_t)(oy + r0 + k) * HW)[oxf + n] = o;
        }
    }
}

static W9 make_w() {
    // reference: sigmah = 9/6, exponent divides by 2*sigmah = 3.0
    double g[9], s = 0.0;
    for (int i = 0; i < 9; ++i) {
        double off = (double)i - 4.5;
        g[i] = exp(-(off * off) / 3.0);
        s += g[i];
    }
    W9 r;
    for (int i = 0; i < 9; ++i) r.w[i] = (float)(g[i] / s);
    return r;
}

extern "C" void kernel_launch(void* const* d_in, const int* in_sizes, int n_in,
                              void* d_out, int out_size, void* d_ws, size_t ws_size,
                              hipStream_t stream) {
    const float* x = (const float*)d_in[0];
    float* out = (float*)d_out;
    W9 w = make_w();
    dim3 grid(HW / 64, HW / TSY, 64);  // 8 x 16 x 64
    lcn_kernel<<<grid, dim3(256), 0, stream>>>(x, out, w);
}